// Round 4
// baseline (3604.128 us; speedup 1.0000x reference)
//
#include <hip/hip_runtime.h>
#include <hip/hip_bf16.h>

// Problem constants
#define BSN   2500   // nodes
#define TT    400    // time steps
#define DIN   16     // input dim
#define HS    32     // hidden dim
#define G4    128    // 4*HS
#define NBLK  157    // blocks (16 rows each)
#define NTHR  512    // 8 waves: 2 waves/SIMD for latency overlap
#define ROWS  16     // nodes per block (MFMA M-tile)
#define MPAD  (NBLK * ROWS)   // 2512 padded rows
#define KPAD  2528            // 79*32 (R3/R7-proven layout)
#define NCHUNK 79
#define ADJW  2536            // adj LDS row stride (ushorts)
#define HPAD  36              // fp32 LDS row pad
#define FLAGSTRIDE 16         // uints between flags (64 B)

// Sentinel: bf16 +inf (0x7F80) is unreachable from tanh output (|q| <= 1,
// and f2bf(NaN) >= 0x7FC0), so a dword == 0x7F807F80 means "not yet written".
#define QSENTW 0x7F807F80u

// workspace layout (bytes) — identical to prior rounds (ring path proven to fit)
#define WS_FLAGS_OFF  0
#define WS_ADJ_OFF    16384
#define WS_ADJ_BYTES  ((size_t)MPAD * KPAD * 2)
#define WS_QT_OFF     (WS_ADJ_OFF + WS_ADJ_BYTES)
#define QT_SLICE      ((size_t)HS * KPAD)
#define WS_NEED_RING  (WS_QT_OFF + (size_t)TT * QT_SLICE * 2)   // ~77.4 MB

typedef __attribute__((ext_vector_type(8))) __bf16 bf16x8;
typedef __attribute__((ext_vector_type(4))) float floatx4;
typedef unsigned short ushort_t;
typedef unsigned long long u64_t;

__device__ __forceinline__ float sigmoid_fast(float v) {
    return 1.0f / (1.0f + __expf(-v));
}
__device__ __forceinline__ float tanh_fast(float v) {
    float e = __expf(2.0f * v);
    return 1.0f - 2.0f / (e + 1.0f);
}
__device__ __forceinline__ ushort_t f2bf(float f) {
    union { float f; unsigned u; } x; x.f = f;
    unsigned r = x.u + 0x7fffu + ((x.u >> 16) & 1u);  // RNE
    return (ushort_t)(r >> 16);
}

// Sentinel: if the cooperative launch is rejected at submit time, out keeps
// 12345.0 -> absmax ~1.23e4 (vs 1.0156 "untouched", 3.9e-3 "correct").
__global__ void sentinel(float* __restrict__ out, int n) {
    int i = blockIdx.x * blockDim.x + threadIdx.x;
    if (i < n) out[i] = 12345.0f;
}

// Per-launch prep (d_ws re-poisoned 0xAA before every timed launch).
// Fills nslices of the q ring with the bf16-inf sentinel in producer-covered
// columns (< MPAD) and ZERO in the never-published pad columns [MPAD,KPAD)
// (so consumers don't wait on them; adj pad columns are zero anyway).
__global__ void prep(const float* __restrict__ adj, ushort_t* __restrict__ adj_bf,
                     ushort_t* __restrict__ qT, unsigned* __restrict__ flags,
                     int nslices) {
    const size_t idx0 = (size_t)blockIdx.x * blockDim.x + threadIdx.x;
    const size_t stride = (size_t)gridDim.x * blockDim.x;
    const size_t total = (size_t)MPAD * KPAD;
    for (size_t idx = idx0; idx < total; idx += stride) {
        int r = (int)(idx / KPAD);
        int k = (int)(idx - (size_t)r * KPAD);
        float v = (r < BSN && k < BSN) ? adj[(size_t)r * BSN + k] : 0.0f;
        adj_bf[idx] = f2bf(v);
    }
    // sentinel-fill the ring (dword granular: MPAD and KPAD both even)
    unsigned* q32 = (unsigned*)qT;
    const size_t q32total = (size_t)nslices * QT_SLICE / 2;
    const int KP2 = KPAD / 2, MP2 = MPAD / 2;
    for (size_t idx = idx0; idx < q32total; idx += stride) {
        int col2 = (int)(idx % (size_t)KP2);
        q32[idx] = (col2 < MP2) ? QSENTW : 0u;
    }
    if (idx0 < NBLK * FLAGSTRIDE) flags[idx0] = 0;
}

#define QLOAD(p) __hip_atomic_load((p), __ATOMIC_RELAXED, __HIP_MEMORY_SCOPE_AGENT)

__device__ __forceinline__ bool has_sent4(const unsigned* d) {
    return ((d[0] == QSENTW) | (d[1] == QSENTW) | (d[2] == QSENTW) | (d[3] == QSENTW));
}

// Ring-mode P2 with sentinel data-polling: issue ALL chunk loads as plain
// b128 (fast path), then retry only sentinel-containing chunks via
// agent-scope u64 atomic loads until the whole wave is clean. Producer 8B
// atomic stores guarantee dword halves never tear, and tanh output can
// never equal the sentinel, so non-sentinel == final data.
template<int NC>
__device__ __forceinline__ void p2_sentinel(const ushort_t* __restrict__ arow,
                                            const ushort_t* __restrict__ q0r,
                                            const ushort_t* __restrict__ q1r,
                                            const int cbeg,
                                            floatx4& acc0, floatx4& acc1) {
    union BV { bf16x8 v; unsigned d[4]; u64_t u[2]; };
    BV b0[NC], b1[NC];
#pragma unroll
    for (int i = 0; i < NC; i++) {
        b0[i].v = *(const bf16x8*)(q0r + (cbeg + i) * 32);
        b1[i].v = *(const bf16x8*)(q1r + (cbeg + i) * 32);
    }
    while (true) {
        unsigned m = 0;
#pragma unroll
        for (int i = 0; i < NC; i++) {
            m |= has_sent4(b0[i].d) ? (1u << i) : 0u;
            m |= has_sent4(b1[i].d) ? (1u << (i + 16)) : 0u;
        }
        if (!__any(m != 0)) break;
#pragma unroll
        for (int i = 0; i < NC; i++) {
            if (m & (1u << i)) {
                const u64_t* p = (const u64_t*)(q0r + (cbeg + i) * 32);
                b0[i].u[0] = QLOAD(p);
                b0[i].u[1] = QLOAD(p + 1);
            }
            if (m & (1u << (i + 16))) {
                const u64_t* p = (const u64_t*)(q1r + (cbeg + i) * 32);
                b1[i].u[0] = QLOAD(p);
                b1[i].u[1] = QLOAD(p + 1);
            }
        }
    }
#pragma unroll
    for (int i = 0; i < NC; i++) {
        bf16x8 av = *(const bf16x8*)(arow + (cbeg + i) * 32);
        acc0 = __builtin_amdgcn_mfma_f32_16x16x32_bf16(av, b0[i].v, acc0, 0, 0, 0);
        acc1 = __builtin_amdgcn_mfma_f32_16x16x32_bf16(av, b1[i].v, acc1, 0, 0, 0);
    }
}

// Persistent cooperative kernel, 512 threads (8 waves), block b owns nodes
// [16b,16b+16).
// R4 ring structure — R2 phase order, FLAG-FREE via sentinel data-polling:
//   P1b (q_lds, R2 float4 form) -> barrier A
//   wave0: packed coalesced publish of slice t (fire-and-forget, NO drain,
//          NO flag) ; all waves: x_lds write (reg prefetch) + own gates
//   P2: sentinel-retry loads (detection rides the data loads) -> RAW barrier
//   P3: agg; c in REGISTER; h_lds; buffered out head -> WAR barrier
//   wave7: every 16 steps flush out_lds as coalesced 64B lines
//   3 barriers/step; zero protocol round-trips beyond the data itself.
// Parity fallback (!RING) keeps the proven flag-based structure.
template<bool RING>
__global__ void __launch_bounds__(NTHR, 2) rgcn_main(
    const float* __restrict__ x,      // [BSN][TT][DIN]
    const float* __restrict__ W_ih,   // [DIN][G4]
    const float* __restrict__ W_hh,   // [HS][G4]
    const float* __restrict__ bias,   // [G4]
    const float* __restrict__ W_q,    // [HS][HS]
    const float* __restrict__ b_q,    // [HS]
    const float* __restrict__ W_d,    // [HS]
    const float* __restrict__ b_d,    // [1]
    const ushort_t* __restrict__ adj_bf, // [MPAD][KPAD] bf16
    ushort_t* __restrict__ qT,        // ring: [TT][HS][KPAD]; parity: [2][HS][KPAD]
    unsigned* __restrict__ flags,     // [NBLK] generation flags (parity path only)
    float* __restrict__ out)          // [BSN][TT]
{
    const int tid  = threadIdx.x;
    const int blk  = blockIdx.x;
    const int base = blk * ROWS;
    const int wv   = tid >> 6;        // wave 0..7
    const int lane = tid & 63;

    __shared__ __align__(16) ushort_t adj_lds[ROWS * ADJW];   // ~81 KB, staged once
    __shared__ __align__(16) float x_lds[ROWS][DIN];
    __shared__ __align__(16) float h_lds[ROWS][HPAD];
    __shared__ __align__(16) float c_lds[ROWS][HPAD];         // parity path only
    __shared__ __align__(16) float q_lds[ROWS][HPAD];
    __shared__ __align__(16) float wq_lds[HS][HS];            // W_q staged once (4 KB)
    __shared__ __align__(16) float out_lds[ROWS][16];         // 16-step out buffer
    __shared__ float gates_lds[ROWS][G4];
    __shared__ float part[8][2][16][16];      // [wave][ntile][row][col], 16 KB

    // ---- per-thread weights, pinned (opaque defs, no remat) ----
    const int u2 = tid & 63;
    float wih0[DIN], wih1[DIN], whh0[HS], whh1[HS];
#pragma unroll
    for (int k = 0; k < DIN; k++) {
        wih0[k] = W_ih[k*G4 + u2]; wih1[k] = W_ih[k*G4 + u2 + 64];
        asm volatile("" : "+v"(wih0[k]), "+v"(wih1[k]));
    }
#pragma unroll
    for (int k = 0; k < HS; k++) {
        whh0[k] = W_hh[k*G4 + u2]; whh1[k] = W_hh[k*G4 + u2 + 64];
        asm volatile("" : "+v"(whh0[k]), "+v"(whh1[k]));
    }
    const float bu0 = bias[u2], bu1 = bias[u2 + 64];

    // P1b/P3 mapping: thread = (node nq = tid>>5, hidden hq = tid&31) — wave-local
    const int hq = tid & 31;
    const int nq = tid >> 5;
    const float bqv = b_q[hq];
    const float wdv = W_d[hq];
    const float bdv = b_d[0];
    float c_reg = 0.0f;               // cell state in a register (ring path)

    // x ownership: wave w stages its own nodes 2w, 2w+1 (lanes < 32)
    const int xnode = (lane < 32) ? (2*wv + (lane >> 4)) : -1;
    const int xk = lane & 15;
    const int xgn = base + xnode;
    const bool xok = (xnode >= 0) && (xgn < BSN);

    // ---- stage adj rows + W_q to LDS once ----
    {
        const int n16_per_row = KPAD / 8;           // 316 uint4 per row
        for (int i = tid; i < ROWS * n16_per_row; i += NTHR) {
            int r = i / n16_per_row, o = i - r * n16_per_row;
            ((uint4*)(adj_lds + r * ADJW))[o] =
                ((const uint4*)(adj_bf + (size_t)(base + r) * KPAD))[o];
        }
    }
    for (int i = tid; i < HS * HS; i += NTHR) (&wq_lds[0][0])[i] = W_q[i];
    for (int i = tid; i < ROWS * HPAD; i += NTHR) {
        (&h_lds[0][0])[i] = 0.0f;
        (&c_lds[0][0])[i] = 0.0f;
    }
    __syncthreads();

    // gates helper: computes both gate halves for node nn (reads x_lds/h_lds)
    auto do_gates = [&](int nn) {
        float a0 = bu0, a1 = bu1;
#pragma unroll
        for (int k4 = 0; k4 < DIN/4; k4++) {
            float4 xv = *(const float4*)&x_lds[nn][k4*4];
            a0 = fmaf(xv.x, wih0[k4*4+0], a0); a1 = fmaf(xv.x, wih1[k4*4+0], a1);
            a0 = fmaf(xv.y, wih0[k4*4+1], a0); a1 = fmaf(xv.y, wih1[k4*4+1], a1);
            a0 = fmaf(xv.z, wih0[k4*4+2], a0); a1 = fmaf(xv.z, wih1[k4*4+2], a1);
            a0 = fmaf(xv.w, wih0[k4*4+3], a0); a1 = fmaf(xv.w, wih1[k4*4+3], a1);
        }
#pragma unroll
        for (int k4 = 0; k4 < HS/4; k4++) {
            float4 hv = *(const float4*)&h_lds[nn][k4*4];
            a0 = fmaf(hv.x, whh0[k4*4+0], a0); a1 = fmaf(hv.x, whh1[k4*4+0], a1);
            a0 = fmaf(hv.y, whh0[k4*4+1], a0); a1 = fmaf(hv.y, whh1[k4*4+1], a1);
            a0 = fmaf(hv.z, whh0[k4*4+2], a0); a1 = fmaf(hv.z, whh1[k4*4+2], a1);
            a0 = fmaf(hv.w, whh0[k4*4+3], a0); a1 = fmaf(hv.w, whh1[k4*4+3], a1);
        }
        gates_lds[nn][u2]      = sigmoid_fast(a0);
        gates_lds[nn][u2 + 64] = (u2 < HS) ? tanh_fast(a1) : sigmoid_fast(a1);
    };

    if constexpr (RING) {
        // x prefetch for t = 0
        float xreg = xok ? x[(size_t)xgn * (TT*DIN) + xk] : 0.0f;

        for (int t = 0; t < TT; t++) {
            ushort_t* qpub = qT + (size_t)t * QT_SLICE;

            // ---- P1b: q_t = tanh(h_{t-1} @ W_q + b_q) (R2 float4 form) ----
            {
                float a = bqv;
#pragma unroll
                for (int k4 = 0; k4 < HS/4; k4++) {
                    float4 hv = *(const float4*)&h_lds[nq][k4*4];
                    a = fmaf(hv.x, wq_lds[k4*4+0][hq], a);
                    a = fmaf(hv.y, wq_lds[k4*4+1][hq], a);
                    a = fmaf(hv.z, wq_lds[k4*4+2][hq], a);
                    a = fmaf(hv.w, wq_lds[k4*4+3][hq], a);
                }
                q_lds[nq][hq] = tanh_fast(a);
            }
            __syncthreads();   // barrier A: q_lds complete before publish reads

            // ---- wave0: coalesced fire-and-forget publish (no drain, no flag) ----
            if (wv == 0) {
                const int r    = lane >> 1;    // h row 0..31
                const int half = lane & 1;     // low/high 8 nodes
                unsigned d[4];
#pragma unroll
                for (int j = 0; j < 4; j++) {
                    const int n0 = half*8 + 2*j;
                    d[j] = (unsigned)f2bf(q_lds[n0][r])
                         | ((unsigned)f2bf(q_lds[n0 + 1][r]) << 16);
                }
                u64_t v0 = (u64_t)d[0] | ((u64_t)d[1] << 32);
                u64_t v1 = (u64_t)d[2] | ((u64_t)d[3] << 32);
                u64_t* prow = (u64_t*)(qpub + (size_t)r * KPAD + base + half*8);
                __hip_atomic_store(prow,     v0, __ATOMIC_RELAXED, __HIP_MEMORY_SCOPE_AGENT);
                __hip_atomic_store(prow + 1, v1, __ATOMIC_RELAXED, __HIP_MEMORY_SCOPE_AGENT);
            }

            // ---- shadow: x_lds write (prefetched) + next prefetch + own gates ----
            if (xnode >= 0) {
                x_lds[xnode][xk] = xok ? xreg : 0.0f;
                const int tn = (t + 1 < TT) ? (t + 1) : (TT - 1);
                if (xok) xreg = x[(size_t)xgn * (TT*DIN) + (size_t)tn * DIN + xk];
            }
            do_gates(2*wv);
            do_gates(2*wv + 1);

            // ---- P2: agg = adj(LDS) @ q(LLC), sentinel-retry ----
            {
                floatx4 acc0 = {0.f,0.f,0.f,0.f}, acc1 = {0.f,0.f,0.f,0.f};
                const int mcol = lane & 15;
                const int kb   = lane >> 4;
                const ushort_t* arow = adj_lds + mcol * ADJW + kb*8;
                const ushort_t* q0r = (const ushort_t*)qpub + (size_t)mcol        * KPAD + kb*8;
                const ushort_t* q1r = (const ushort_t*)qpub + (size_t)(mcol + 16) * KPAD + kb*8;
                if (wv < 7) p2_sentinel<10>(arow, q0r, q1r, wv * 10, acc0, acc1);
                else        p2_sentinel<9>(arow, q0r, q1r, 70,       acc0, acc1);
#pragma unroll
                for (int r = 0; r < 4; r++) {
                    part[wv][0][kb*4 + r][mcol] = acc0[r];
                    part[wv][1][kb*4 + r][mcol] = acc1[r];
                }
            }
            __syncthreads();   // RAW: part[] (P2 -> P3)

            // ---- P3: cell/hidden update + buffered out head ----
            {
                const int ntile = hq >> 4, col = hq & 15;
                float agg = 0.0f;
#pragma unroll
                for (int w = 0; w < 8; w++) agg += part[w][ntile][nq][col];
                float iv = gates_lds[nq][hq];
                float fv = gates_lds[nq][HS + hq];
                float gv = gates_lds[nq][2*HS + hq];
                float ov = gates_lds[nq][3*HS + hq];
                float cv = fv * (c_reg + agg) + iv * gv;
                float hvv = ov * tanh_fast(cv);
                c_reg = cv;
                h_lds[nq][hq] = hvv;
                float p = hvv * wdv;
                p += __shfl_xor(p, 16);
                p += __shfl_xor(p, 8);
                p += __shfl_xor(p, 4);
                p += __shfl_xor(p, 2);
                p += __shfl_xor(p, 1);
                if (hq == 0) out_lds[nq][t & 15] = p + bdv;
            }
            __syncthreads();   // WAR: part[]/q_lds/h_lds/out_lds

            // ---- wave7: flush 16 steps of out as coalesced 64B lines ----
            if (wv == 7 && (t & 15) == 15) {
                const int node = lane >> 2, qtr = lane & 3;
                const int gn = base + node;
                if (gn < BSN) {
                    *(float4*)(out + (size_t)gn * TT + (t - 15) + qtr * 4) =
                        *(const float4*)&out_lds[node][qtr * 4];
                }
            }
        }
    } else {
        // ================= parity fallback: proven flag-based structure =================
        for (int t = 0; t < TT; t++) {
            const unsigned phase = (unsigned)(t + 1);
            ushort_t* qbuf = qT + (size_t)(t & 1) * QT_SLICE;

            {
                float a = bqv;
#pragma unroll
                for (int k4 = 0; k4 < HS/4; k4++) {
                    float4 hv = *(const float4*)&h_lds[nq][k4*4];
                    a = fmaf(hv.x, wq_lds[k4*4+0][hq], a);
                    a = fmaf(hv.y, wq_lds[k4*4+1][hq], a);
                    a = fmaf(hv.z, wq_lds[k4*4+2][hq], a);
                    a = fmaf(hv.w, wq_lds[k4*4+3][hq], a);
                }
                q_lds[nq][hq] = tanh_fast(a);
            }
            __syncthreads();

            if (tid < 256) {
                const int h0 = tid >> 3;
                const int pr = tid & 7;
                unsigned val = (unsigned)f2bf(q_lds[2*pr][h0])
                             | ((unsigned)f2bf(q_lds[2*pr + 1][h0]) << 16);
                unsigned* p = (unsigned*)(qbuf + (size_t)h0 * KPAD + base) + pr;
                __hip_atomic_store(p, val, __ATOMIC_RELAXED, __HIP_MEMORY_SCOPE_AGENT);
            }
            if (lane < 32) {
                const int node = 2*wv + (lane >> 4), k = lane & 15;
                const int gn = base + node;
                x_lds[node][k] = (gn < BSN) ? x[(size_t)gn * (TT*DIN) + (size_t)t*DIN + k] : 0.0f;
            }
            do_gates(2*wv);
            do_gates(2*wv + 1);
            asm volatile("s_waitcnt vmcnt(0)" ::: "memory");
            __syncthreads();
            if (tid == 0) {
                __hip_atomic_store(flags + blk * FLAGSTRIDE, phase,
                                   __ATOMIC_RELAXED, __HIP_MEMORY_SCOPE_AGENT);
            }
            if (tid < NBLK) {
                const unsigned* f = flags + tid * FLAGSTRIDE;
                while (QLOAD(f) < phase) {}
            }
            __syncthreads();

            {
                floatx4 acc0 = {0.f,0.f,0.f,0.f}, acc1 = {0.f,0.f,0.f,0.f};
                const int mcol = lane & 15;
                const int kb   = lane >> 4;
                const ushort_t* arow = adj_lds + mcol * ADJW + kb*8;
                const u64_t* q0 = (const u64_t*)(qbuf + (size_t)mcol        * KPAD) + kb*2;
                const u64_t* q1 = (const u64_t*)(qbuf + (size_t)(mcol + 16) * KPAD) + kb*2;
                const int cbeg = wv * 10;
                const int cend = (cbeg + 10 < NCHUNK) ? cbeg + 10 : NCHUNK;
                for (int c = cbeg; c < cend; c++) {
                    bf16x8 av = *(const bf16x8*)(arow + c*32);
                    union { u64_t u[2]; bf16x8 v; } b0, b1;
                    b0.u[0] = QLOAD(q0 + c*8);
                    b0.u[1] = QLOAD(q0 + c*8 + 1);
                    b1.u[0] = QLOAD(q1 + c*8);
                    b1.u[1] = QLOAD(q1 + c*8 + 1);
                    acc0 = __builtin_amdgcn_mfma_f32_16x16x32_bf16(av, b0.v, acc0, 0, 0, 0);
                    acc1 = __builtin_amdgcn_mfma_f32_16x16x32_bf16(av, b1.v, acc1, 0, 0, 0);
                }
#pragma unroll
                for (int r = 0; r < 4; r++) {
                    part[wv][0][kb*4 + r][mcol] = acc0[r];
                    part[wv][1][kb*4 + r][mcol] = acc1[r];
                }
            }
            __syncthreads();

            {
                const int ntile = hq >> 4, col = hq & 15;
                float agg = 0.0f;
#pragma unroll
                for (int w = 0; w < 8; w++) agg += part[w][ntile][nq][col];
                float iv = gates_lds[nq][hq];
                float fv = gates_lds[nq][HS + hq];
                float gv = gates_lds[nq][2*HS + hq];
                float ov = gates_lds[nq][3*HS + hq];
                float cv = fv * (c_lds[nq][hq] + agg) + iv * gv;
                float hv = ov * tanh_fast(cv);
                c_lds[nq][hq] = cv;
                h_lds[nq][hq] = hv;
                float p = hv * wdv;
                p += __shfl_xor(p, 16);
                p += __shfl_xor(p, 8);
                p += __shfl_xor(p, 4);
                p += __shfl_xor(p, 2);
                p += __shfl_xor(p, 1);
                if (hq == 0) {
                    int gn = base + nq;
                    if (gn < BSN) out[(size_t)gn * TT + t] = p + bdv;
                }
            }
            __syncthreads();
        }
    }
}

extern "C" void kernel_launch(void* const* d_in, const int* in_sizes, int n_in,
                              void* d_out, int out_size, void* d_ws, size_t ws_size,
                              hipStream_t stream) {
    const float* x    = (const float*)d_in[0];
    const float* adj  = (const float*)d_in[1];
    const float* W_ih = (const float*)d_in[2];
    const float* W_hh = (const float*)d_in[3];
    const float* bias = (const float*)d_in[4];
    const float* W_q  = (const float*)d_in[5];
    const float* b_q  = (const float*)d_in[6];
    const float* W_d  = (const float*)d_in[7];
    const float* b_d  = (const float*)d_in[8];
    float* out = (float*)d_out;

    unsigned* flags = (unsigned*)((char*)d_ws + WS_FLAGS_OFF);
    ushort_t* adj_bf = (ushort_t*)((char*)d_ws + WS_ADJ_OFF);
    ushort_t* qT = (ushort_t*)((char*)d_ws + WS_QT_OFF);

    const bool ring = (ws_size >= WS_NEED_RING);   // constant across calls -> graph-safe
    int nslices = ring ? TT : 2;

    // sentinel first: if the cooperative launch below is rejected, out keeps 12345.0
    hipLaunchKernelGGL(sentinel, dim3((out_size + 255) / 256), dim3(256), 0, stream,
                       out, out_size);
    hipLaunchKernelGGL(prep, dim3(2048), dim3(256), 0, stream, adj, adj_bf, qT, flags,
                       nslices);

    const ushort_t* adj_bf_c = adj_bf;
    void* args[] = {
        (void*)&x, (void*)&W_ih, (void*)&W_hh, (void*)&bias, (void*)&W_q,
        (void*)&b_q, (void*)&W_d, (void*)&b_d, (void*)&adj_bf_c, (void*)&qT,
        (void*)&flags, (void*)&out
    };
    if (ring) {
        hipLaunchCooperativeKernel((void*)&rgcn_main<true>, dim3(NBLK), dim3(NTHR),
                                   args, 0, stream);
    } else {
        hipLaunchCooperativeKernel((void*)&rgcn_main<false>, dim3(NBLK), dim3(NTHR),
                                   args, 0, stream);
    }
}

// Round 5
// 1830.726 us; speedup vs baseline: 1.9687x; 1.9687x over previous
//
#include <hip/hip_runtime.h>
#include <hip/hip_bf16.h>

// Problem constants
#define BSN   2500   // nodes
#define TT    400    // time steps
#define DIN   16     // input dim
#define HS    32     // hidden dim
#define G4    128    // 4*HS
#define NBLK  157    // blocks (16 rows each)
#define NTHR  512    // 8 waves: 2 waves/SIMD for latency overlap
#define ROWS  16     // nodes per block (MFMA M-tile)
#define MPAD  (NBLK * ROWS)   // 2512 padded rows
#define KPAD  2528            // 79*32 (proven adj layout)
#define NCHUNK 79
#define ADJW  2536            // adj LDS row stride (ushorts)
#define HPAD  36              // fp32 LDS row pad
#define FLAGSTRIDE 16         // uints between flags (64 B)

// Fragment-ordered q slice (ring mode):
//   region r (r=0: h rows 0-15, r=1: h rows 16-31), chunk c (32 nodes),
//   byte addr = r*REGBYTES + c*1024 + lane*16 holds the 16 B MFMA-B fragment
//   for lane `lane` of chunk c. Producer block b (c=b>>1, half=b&1) owns the
//   contiguous 512 B [c*1024+half*512, +512) of each region.
//   Slice bytes = 2*NCHUNK*1024 = 161792 = HS*KPAD*2 (same as old layout).
#define REGUS   (NCHUNK * 512)          // region size in ushorts (40448)

// workspace layout (bytes) — identical to prior rounds
#define WS_FLAGS_OFF  0
#define WS_ADJ_OFF    16384
#define WS_ADJ_BYTES  ((size_t)MPAD * KPAD * 2)
#define WS_QT_OFF     (WS_ADJ_OFF + WS_ADJ_BYTES)
#define QT_SLICE      ((size_t)HS * KPAD)
#define WS_NEED_RING  (WS_QT_OFF + (size_t)TT * QT_SLICE * 2)   // ~77.4 MB

typedef __attribute__((ext_vector_type(8))) __bf16 bf16x8;
typedef __attribute__((ext_vector_type(4))) float floatx4;
typedef unsigned short ushort_t;
typedef unsigned long long u64_t;

__device__ __forceinline__ float sigmoid_fast(float v) {
    return 1.0f / (1.0f + __expf(-v));
}
__device__ __forceinline__ float tanh_fast(float v) {
    float e = __expf(2.0f * v);
    return 1.0f - 2.0f / (e + 1.0f);
}
__device__ __forceinline__ ushort_t f2bf(float f) {
    union { float f; unsigned u; } x; x.f = f;
    unsigned r = x.u + 0x7fffu + ((x.u >> 16) & 1u);  // RNE
    return (ushort_t)(r >> 16);
}

// Sentinel: if the cooperative launch is rejected at submit time, out keeps
// 12345.0 -> absmax ~1.23e4 (vs 1.0156 "untouched", 3.9e-3 "correct").
__global__ void sentinel(float* __restrict__ out, int n) {
    int i = blockIdx.x * blockDim.x + threadIdx.x;
    if (i < n) out[i] = 12345.0f;
}

// Per-launch prep (d_ws re-poisoned 0xAA before every timed launch) — R2 form.
__global__ void prep(const float* __restrict__ adj, ushort_t* __restrict__ adj_bf,
                     ushort_t* __restrict__ qT, unsigned* __restrict__ flags) {
    const size_t idx0 = (size_t)blockIdx.x * blockDim.x + threadIdx.x;
    const size_t stride = (size_t)gridDim.x * blockDim.x;
    const size_t total = (size_t)MPAD * KPAD;
    for (size_t idx = idx0; idx < total; idx += stride) {
        int r = (int)(idx / KPAD);
        int k = (int)(idx - (size_t)r * KPAD);
        float v = (r < BSN && k < BSN) ? adj[(size_t)r * BSN + k] : 0.0f;
        adj_bf[idx] = f2bf(v);
    }
    for (size_t idx = idx0; idx < 2 * QT_SLICE; idx += stride) qT[idx] = 0;
    if (idx0 < NBLK * FLAGSTRIDE) flags[idx0] = 0;
}

#define QLOAD(p) __hip_atomic_load((p), __ATOMIC_RELAXED, __HIP_MEMORY_SCOPE_AGENT)

// Ring-mode P2, fragment layout: chunk c's B-fragment for this lane is the
// 16 B at q0/q1 + c*512 ushorts. Fully-coalesced 1 KB per chunk per wave.
template<int NC>
__device__ __forceinline__ void p2_frag(const ushort_t* __restrict__ arow,
                                        const ushort_t* __restrict__ q0,
                                        const ushort_t* __restrict__ q1,
                                        const int cbeg,
                                        floatx4& acc0, floatx4& acc1) {
    bf16x8 b0[NC], b1[NC];
#pragma unroll
    for (int i = 0; i < NC; i++) {
        b0[i] = *(const bf16x8*)(q0 + (size_t)(cbeg + i) * 512);
        b1[i] = *(const bf16x8*)(q1 + (size_t)(cbeg + i) * 512);
    }
#pragma unroll
    for (int i = 0; i < NC; i++) {
        bf16x8 av = *(const bf16x8*)(arow + (cbeg + i) * 32);
        acc0 = __builtin_amdgcn_mfma_f32_16x16x32_bf16(av, b0[i], acc0, 0, 0, 0);
        acc1 = __builtin_amdgcn_mfma_f32_16x16x32_bf16(av, b1[i], acc1, 0, 0, 0);
    }
}

// Persistent cooperative kernel, 512 threads (8 waves), block b owns nodes
// [16b,16b+16).
// R5 ring structure — R2 protocol (flags, drain, per-wave poll) with:
//   * fragment-ordered q slices (coalesced publish AND consume)
//   * dedicated wave0: publish+drain+flag only (no gates, no P2 chunks);
//     waves 1-7 split the 79 chunks 12,12,12,11,11,11,10 (balanced RAW arrival)
//   * part[] ping-pong -> WAR barrier removed (~2.06 barriers/step)
//   * c in registers, out buffered 16 steps, x register prefetch
// Cross-wave hazard audit (no WAR): q_lds pack-read(t) precedes wave0's RAW(t)
// arrival, writers P1b(t+1) run after RAW(t) -> safe. h_lds[0,1] written by
// wave0 P3(t), read by waves1,2 in shadow(t+1) AFTER barA(t+1) -> safe.
// part[p] writers at P2(t+1) sit after barA(t+1) > all P3(t-1) readers -> safe.
// out_lds flush gets a dedicated barrier every 16 steps.
// Parity fallback (!RING) keeps the R2-proven 5-barrier flag structure.
template<bool RING>
__global__ void __launch_bounds__(NTHR, 2) rgcn_main(
    const float* __restrict__ x,      // [BSN][TT][DIN]
    const float* __restrict__ W_ih,   // [DIN][G4]
    const float* __restrict__ W_hh,   // [HS][G4]
    const float* __restrict__ bias,   // [G4]
    const float* __restrict__ W_q,    // [HS][HS]
    const float* __restrict__ b_q,    // [HS]
    const float* __restrict__ W_d,    // [HS]
    const float* __restrict__ b_d,    // [1]
    const ushort_t* __restrict__ adj_bf, // [MPAD][KPAD] bf16
    ushort_t* __restrict__ qT,        // ring: [TT] fragment slices; parity: [2][HS][KPAD]
    unsigned* __restrict__ flags,     // [NBLK] generation flags, FLAGSTRIDE apart
    float* __restrict__ out)          // [BSN][TT]
{
    const int tid  = threadIdx.x;
    const int blk  = blockIdx.x;
    const int base = blk * ROWS;
    const int wv   = tid >> 6;        // wave 0..7
    const int lane = tid & 63;

    __shared__ __align__(16) ushort_t adj_lds[ROWS * ADJW];   // ~81 KB, staged once
    __shared__ __align__(16) float x_lds[ROWS][DIN];
    __shared__ __align__(16) float h_lds[ROWS][HPAD];
    __shared__ __align__(16) float c_lds[ROWS][HPAD];         // parity path only
    __shared__ __align__(16) float q_lds[ROWS][HPAD];
    __shared__ __align__(16) float wq_lds[HS][HS];            // W_q staged once (4 KB)
    __shared__ __align__(16) float out_lds[ROWS][16];         // 16-step out buffer
    __shared__ float gates_lds[ROWS][G4];
    __shared__ float part[2][7][2][16][16];   // ping-pong, waves 1-7, 28 KB

    // ---- per-thread weights, pinned (opaque defs, no remat) ----
    const int u2 = tid & 63;
    float wih0[DIN], wih1[DIN], whh0[HS], whh1[HS];
#pragma unroll
    for (int k = 0; k < DIN; k++) {
        wih0[k] = W_ih[k*G4 + u2]; wih1[k] = W_ih[k*G4 + u2 + 64];
        asm volatile("" : "+v"(wih0[k]), "+v"(wih1[k]));
    }
#pragma unroll
    for (int k = 0; k < HS; k++) {
        whh0[k] = W_hh[k*G4 + u2]; whh1[k] = W_hh[k*G4 + u2 + 64];
        asm volatile("" : "+v"(whh0[k]), "+v"(whh1[k]));
    }
    const float bu0 = bias[u2], bu1 = bias[u2 + 64];

    // P1b/P3 mapping: thread = (node nq = tid>>5, hidden hq = tid&31) — wave-local
    const int hq = tid & 31;
    const int nq = tid >> 5;
    const float bqv = b_q[hq];
    const float wdv = W_d[hq];
    const float bdv = b_d[0];
    float c_reg = 0.0f;               // cell state in a register (ring path)

    // chunk split for waves 1-7: 12,12,12,11,11,11,10 (sum 79)
    int cbeg = 0, nch = 0;
    if (wv >= 1 && wv <= 3)      { cbeg = (wv - 1) * 12;      nch = 12; }
    else if (wv >= 4 && wv <= 6) { cbeg = 36 + (wv - 4) * 11; nch = 11; }
    else if (wv == 7)            { cbeg = 69;                 nch = 10; }
    // producers for this wave's chunks: [2*cbeg, 2*(cbeg+nch)) capped at NBLK
    const int pollbase = 2 * cbeg;
    const int pollcnt  = (wv == 0) ? 0
                       : ((2 * (cbeg + nch) < NBLK ? 2 * (cbeg + nch) : NBLK) - pollbase);
    const unsigned* pollf = flags + (size_t)(pollbase + lane) * FLAGSTRIDE;
    const bool dopoll = (wv >= 1) && (lane < pollcnt);

    // x ownership (ring): wave w>=1 stages nodes 2w,2w+1; waves 1,2 also 0,1
    int xnode = -1, xk = lane & 15;
    if (wv >= 1 && lane < 32)                   xnode = 2*wv + (lane >> 4);
    else if ((wv == 1 || wv == 2) && lane < 48) xnode = wv - 1;
    const int xgn = base + xnode;
    const bool xok = (xnode >= 0) && (xgn < BSN);

    // ---- stage adj rows + W_q to LDS once ----
    {
        const int n16_per_row = KPAD / 8;           // 316 uint4 per row
        for (int i = tid; i < ROWS * n16_per_row; i += NTHR) {
            int r = i / n16_per_row, o = i - r * n16_per_row;
            ((uint4*)(adj_lds + r * ADJW))[o] =
                ((const uint4*)(adj_bf + (size_t)(base + r) * KPAD))[o];
        }
    }
    for (int i = tid; i < HS * HS; i += NTHR) (&wq_lds[0][0])[i] = W_q[i];
    for (int i = tid; i < ROWS * HPAD; i += NTHR) {
        (&h_lds[0][0])[i] = 0.0f;
        (&c_lds[0][0])[i] = 0.0f;
    }
    __syncthreads();

    // gates helper: computes both gate halves for node nn (reads x_lds/h_lds)
    auto do_gates = [&](int nn) {
        float a0 = bu0, a1 = bu1;
#pragma unroll
        for (int k4 = 0; k4 < DIN/4; k4++) {
            float4 xv = *(const float4*)&x_lds[nn][k4*4];
            a0 = fmaf(xv.x, wih0[k4*4+0], a0); a1 = fmaf(xv.x, wih1[k4*4+0], a1);
            a0 = fmaf(xv.y, wih0[k4*4+1], a0); a1 = fmaf(xv.y, wih1[k4*4+1], a1);
            a0 = fmaf(xv.z, wih0[k4*4+2], a0); a1 = fmaf(xv.z, wih1[k4*4+2], a1);
            a0 = fmaf(xv.w, wih0[k4*4+3], a0); a1 = fmaf(xv.w, wih1[k4*4+3], a1);
        }
#pragma unroll
        for (int k4 = 0; k4 < HS/4; k4++) {
            float4 hv = *(const float4*)&h_lds[nn][k4*4];
            a0 = fmaf(hv.x, whh0[k4*4+0], a0); a1 = fmaf(hv.x, whh1[k4*4+0], a1);
            a0 = fmaf(hv.y, whh0[k4*4+1], a0); a1 = fmaf(hv.y, whh1[k4*4+1], a1);
            a0 = fmaf(hv.z, whh0[k4*4+2], a0); a1 = fmaf(hv.z, whh1[k4*4+2], a1);
            a0 = fmaf(hv.w, whh0[k4*4+3], a0); a1 = fmaf(hv.w, whh1[k4*4+3], a1);
        }
        gates_lds[nn][u2]      = sigmoid_fast(a0);
        gates_lds[nn][u2 + 64] = (u2 < HS) ? tanh_fast(a1) : sigmoid_fast(a1);
    };

    if constexpr (RING) {
        // x prefetch for t = 0
        float xreg = xok ? x[(size_t)xgn * (TT*DIN) + xk] : 0.0f;

        // publish constants (wave0): block b -> chunk c=b>>1, half=b&1
        const int pc    = blk >> 1;
        const int phalf = blk & 1;
        const int preg  = lane >> 5;       // region 0/1
        const int pidx  = lane & 31;
        const int ph    = (pidx & 15) + 16 * preg;   // q_lds h col
        const int pln0  = (pidx >> 4) * 8;           // first of 8 nodes

        for (int t = 0; t < TT; t++) {
            const unsigned phase = (unsigned)(t + 1);
            const ushort_t* qslice = qT + (size_t)t * QT_SLICE;

            // ---- P1b: q_t = tanh(h_{t-1} @ W_q + b_q) ----
            {
                float a = bqv;
#pragma unroll
                for (int k4 = 0; k4 < HS/4; k4++) {
                    float4 hv = *(const float4*)&h_lds[nq][k4*4];
                    a = fmaf(hv.x, wq_lds[k4*4+0][hq], a);
                    a = fmaf(hv.y, wq_lds[k4*4+1][hq], a);
                    a = fmaf(hv.z, wq_lds[k4*4+2][hq], a);
                    a = fmaf(hv.w, wq_lds[k4*4+3][hq], a);
                }
                q_lds[nq][hq] = tanh_fast(a);
            }
            __syncthreads();   // barrier A: q_lds complete; orders prior P3 writes too

            if (wv == 0) {
                // ---- dedicated publish wave: 2x 8B atomic stores into this
                //      block's contiguous 512 B strip of each region ----
                unsigned d[4];
#pragma unroll
                for (int j = 0; j < 4; j++) {
                    const int n0 = pln0 + 2*j;
                    d[j] = (unsigned)f2bf(q_lds[n0][ph])
                         | ((unsigned)f2bf(q_lds[n0 + 1][ph]) << 16);
                }
                u64_t v0 = (u64_t)d[0] | ((u64_t)d[1] << 32);
                u64_t v1 = (u64_t)d[2] | ((u64_t)d[3] << 32);
                u64_t* dst = (u64_t*)((ushort_t*)qslice + (size_t)preg * REGUS
                                      + (size_t)pc * 512 + phalf * 256 + pidx * 8);
                __hip_atomic_store(dst,     v0, __ATOMIC_RELAXED, __HIP_MEMORY_SCOPE_AGENT);
                __hip_atomic_store(dst + 1, v1, __ATOMIC_RELAXED, __HIP_MEMORY_SCOPE_AGENT);
                asm volatile("s_waitcnt vmcnt(0)" ::: "memory");
                if (lane == 0) {
                    __hip_atomic_store(flags + blk * FLAGSTRIDE, phase,
                                       __ATOMIC_RELAXED, __HIP_MEMORY_SCOPE_AGENT);
                }
            } else {
                // ---- shadow: x_lds write (prefetched) + next prefetch + gates ----
                if (xnode >= 0) {
                    x_lds[xnode][xk] = xok ? xreg : 0.0f;
                    const int tn = (t + 1 < TT) ? (t + 1) : (TT - 1);
                    if (xok) xreg = x[(size_t)xgn * (TT*DIN) + (size_t)tn * DIN + xk];
                }
                do_gates(2*wv);
                do_gates(2*wv + 1);
                if (wv <= 2) do_gates(wv - 1);   // cover wave 0's nodes
            }

            // ---- per-wave poll of this wave's producers ----
            if (dopoll) {
                while (QLOAD(pollf) < phase) {}
            }

            // ---- P2 (waves 1-7): agg = adj(LDS) @ q(LLC), coalesced frags ----
            if (wv >= 1) {
                floatx4 acc0 = {0.f,0.f,0.f,0.f}, acc1 = {0.f,0.f,0.f,0.f};
                const int mcol = lane & 15;
                const int kb   = lane >> 4;
                const ushort_t* arow = adj_lds + mcol * ADJW + kb*8;
                const ushort_t* q0 = qslice + (size_t)lane * 8;
                const ushort_t* q1 = qslice + (size_t)REGUS + (size_t)lane * 8;
                if (wv <= 3)      p2_frag<12>(arow, q0, q1, cbeg, acc0, acc1);
                else if (wv <= 6) p2_frag<11>(arow, q0, q1, cbeg, acc0, acc1);
                else              p2_frag<10>(arow, q0, q1, cbeg, acc0, acc1);
#pragma unroll
                for (int r = 0; r < 4; r++) {
                    part[t & 1][wv - 1][0][kb*4 + r][mcol] = acc0[r];
                    part[t & 1][wv - 1][1][kb*4 + r][mcol] = acc1[r];
                }
            }
            __syncthreads();   // RAW: part[] (P2 -> P3)

            // ---- P3: cell/hidden update + buffered out head ----
            {
                const int ntile = hq >> 4, col = hq & 15;
                float agg = 0.0f;
#pragma unroll
                for (int j = 0; j < 7; j++) agg += part[t & 1][j][ntile][nq][col];
                float iv = gates_lds[nq][hq];
                float fv = gates_lds[nq][HS + hq];
                float gv = gates_lds[nq][2*HS + hq];
                float ov = gates_lds[nq][3*HS + hq];
                float cv = fv * (c_reg + agg) + iv * gv;
                float hvv = ov * tanh_fast(cv);
                c_reg = cv;
                h_lds[nq][hq] = hvv;
                float p = hvv * wdv;
                p += __shfl_xor(p, 16);
                p += __shfl_xor(p, 8);
                p += __shfl_xor(p, 4);
                p += __shfl_xor(p, 2);
                p += __shfl_xor(p, 1);
                if (hq == 0) out_lds[nq][t & 15] = p + bdv;
            }

            // ---- every 16 steps: barrier + coalesced out flush (wave 7) ----
            if ((t & 15) == 15) {
                __syncthreads();
                if (wv == 7) {
                    const int node = lane >> 2, qtr = lane & 3;
                    const int gn = base + node;
                    if (gn < BSN) {
                        *(float4*)(out + (size_t)gn * TT + (t - 15) + qtr * 4) =
                            *(const float4*)&out_lds[node][qtr * 4];
                    }
                }
            }
        }
    } else {
        // ================= parity fallback: R2-proven structure =================
        for (int t = 0; t < TT; t++) {
            const unsigned phase = (unsigned)(t + 1);
            ushort_t* qbuf = qT + (size_t)(t & 1) * QT_SLICE;

            {
                float a = bqv;
#pragma unroll
                for (int k4 = 0; k4 < HS/4; k4++) {
                    float4 hv = *(const float4*)&h_lds[nq][k4*4];
                    a = fmaf(hv.x, wq_lds[k4*4+0][hq], a);
                    a = fmaf(hv.y, wq_lds[k4*4+1][hq], a);
                    a = fmaf(hv.z, wq_lds[k4*4+2][hq], a);
                    a = fmaf(hv.w, wq_lds[k4*4+3][hq], a);
                }
                q_lds[nq][hq] = tanh_fast(a);
            }
            __syncthreads();

            if (tid < 256) {
                const int h0 = tid >> 3;
                const int pr = tid & 7;
                unsigned val = (unsigned)f2bf(q_lds[2*pr][h0])
                             | ((unsigned)f2bf(q_lds[2*pr + 1][h0]) << 16);
                unsigned* p = (unsigned*)(qbuf + (size_t)h0 * KPAD + base) + pr;
                __hip_atomic_store(p, val, __ATOMIC_RELAXED, __HIP_MEMORY_SCOPE_AGENT);
            }
            if (lane < 32) {
                const int node = 2*wv + (lane >> 4), k = lane & 15;
                const int gn = base + node;
                x_lds[node][k] = (gn < BSN) ? x[(size_t)gn * (TT*DIN) + (size_t)t*DIN + k] : 0.0f;
            }
            do_gates(2*wv);
            do_gates(2*wv + 1);
            asm volatile("s_waitcnt vmcnt(0)" ::: "memory");
            __syncthreads();
            if (tid == 0) {
                __hip_atomic_store(flags + blk * FLAGSTRIDE, phase,
                                   __ATOMIC_RELAXED, __HIP_MEMORY_SCOPE_AGENT);
            }
            if (tid < NBLK) {
                const unsigned* f = flags + tid * FLAGSTRIDE;
                while (QLOAD(f) < phase) {}
            }
            __syncthreads();

            {
                floatx4 acc0 = {0.f,0.f,0.f,0.f}, acc1 = {0.f,0.f,0.f,0.f};
                const int mcol = lane & 15;
                const int kb   = lane >> 4;
                const ushort_t* arow = adj_lds + mcol * ADJW + kb*8;
                const u64_t* q0 = (const u64_t*)(qbuf + (size_t)mcol        * KPAD) + kb*2;
                const u64_t* q1 = (const u64_t*)(qbuf + (size_t)(mcol + 16) * KPAD) + kb*2;
                const int cb2 = wv * 10;
                const int ce2 = (cb2 + 10 < NCHUNK) ? cb2 + 10 : NCHUNK;
                for (int c = cb2; c < ce2; c++) {
                    bf16x8 av = *(const bf16x8*)(arow + c*32);
                    union { u64_t u[2]; bf16x8 v; } b0, b1;
                    b0.u[0] = QLOAD(q0 + c*8);
                    b0.u[1] = QLOAD(q0 + c*8 + 1);
                    b1.u[0] = QLOAD(q1 + c*8);
                    b1.u[1] = QLOAD(q1 + c*8 + 1);
                    acc0 = __builtin_amdgcn_mfma_f32_16x16x32_bf16(av, b0.v, acc0, 0, 0, 0);
                    acc1 = __builtin_amdgcn_mfma_f32_16x16x32_bf16(av, b1.v, acc1, 0, 0, 0);
                }
                // reuse part[0][...] slots 0..6 won't fit 8 waves; parity path
                // keeps its own mapping in part[0..1] by wave parity split:
                part[wv >> 2][(wv & 3) + ((wv >> 2) ? 3 : 0)][0][kb*4 + 0][mcol] = acc0[0];
                // (see note below — parity path uses dedicated layout)
#pragma unroll
                for (int r = 0; r < 4; r++) {
                    part[0][wv % 7][0][kb*4 + r][mcol] = 0.0f;  // placeholder, overwritten
                }
                // Simpler, correct: store into a flat view of part[] by wave.
                float* pw = &part[0][0][0][0][0] + (size_t)wv * 2 * 16 * 16;
#pragma unroll
                for (int r = 0; r < 4; r++) {
                    pw[(0*16 + kb*4 + r) * 16 + mcol] = acc0[r];
                    pw[(1*16 + kb*4 + r) * 16 + mcol] = acc1[r];
                }
            }
            __syncthreads();

            {
                const int ntile = hq >> 4, col = hq & 15;
                float agg = 0.0f;
                const float* pbase = &part[0][0][0][0][0];
#pragma unroll
                for (int w = 0; w < 8; w++) {
                    agg += pbase[(size_t)w * 2 * 16 * 16 + (ntile*16 + nq) * 16 + col];
                }
                float iv = gates_lds[nq][hq];
                float fv = gates_lds[nq][HS + hq];
                float gv = gates_lds[nq][2*HS + hq];
                float ov = gates_lds[nq][3*HS + hq];
                float cv = fv * (c_lds[nq][hq] + agg) + iv * gv;
                float hv = ov * tanh_fast(cv);
                c_lds[nq][hq] = cv;
                h_lds[nq][hq] = hv;
                float p = hv * wdv;
                p += __shfl_xor(p, 16);
                p += __shfl_xor(p, 8);
                p += __shfl_xor(p, 4);
                p += __shfl_xor(p, 2);
                p += __shfl_xor(p, 1);
                if (hq == 0) {
                    int gn = base + nq;
                    if (gn < BSN) out[(size_t)gn * TT + t] = p + bdv;
                }
            }
            __syncthreads();
        }
    }
}

extern "C" void kernel_launch(void* const* d_in, const int* in_sizes, int n_in,
                              void* d_out, int out_size, void* d_ws, size_t ws_size,
                              hipStream_t stream) {
    const float* x    = (const float*)d_in[0];
    const float* adj  = (const float*)d_in[1];
    const float* W_ih = (const float*)d_in[2];
    const float* W_hh = (const float*)d_in[3];
    const float* bias = (const float*)d_in[4];
    const float* W_q  = (const float*)d_in[5];
    const float* b_q  = (const float*)d_in[6];
    const float* W_d  = (const float*)d_in[7];
    const float* b_d  = (const float*)d_in[8];
    float* out = (float*)d_out;

    unsigned* flags = (unsigned*)((char*)d_ws + WS_FLAGS_OFF);
    ushort_t* adj_bf = (ushort_t*)((char*)d_ws + WS_ADJ_OFF);
    ushort_t* qT = (ushort_t*)((char*)d_ws + WS_QT_OFF);

    const bool ring = (ws_size >= WS_NEED_RING);   // constant across calls -> graph-safe

    // sentinel first: if the cooperative launch below is rejected, out keeps 12345.0
    hipLaunchKernelGGL(sentinel, dim3((out_size + 255) / 256), dim3(256), 0, stream,
                       out, out_size);
    hipLaunchKernelGGL(prep, dim3(2048), dim3(256), 0, stream, adj, adj_bf, qT, flags);

    const ushort_t* adj_bf_c = adj_bf;
    void* args[] = {
        (void*)&x, (void*)&W_ih, (void*)&W_hh, (void*)&bias, (void*)&W_q,
        (void*)&b_q, (void*)&W_d, (void*)&b_d, (void*)&adj_bf_c, (void*)&qT,
        (void*)&flags, (void*)&out
    };
    if (ring) {
        hipLaunchCooperativeKernel((void*)&rgcn_main<true>, dim3(NBLK), dim3(NTHR),
                                   args, 0, stream);
    } else {
        hipLaunchCooperativeKernel((void*)&rgcn_main<false>, dim3(NBLK), dim3(NTHR),
                                   args, 0, stream);
    }
}

// Round 6
// 1795.511 us; speedup vs baseline: 2.0073x; 1.0196x over previous
//
#include <hip/hip_runtime.h>
#include <hip/hip_bf16.h>

// Problem constants
#define BSN   2500   // nodes
#define TT    400    // time steps
#define DIN   16     // input dim
#define HS    32     // hidden dim
#define G4    128    // 4*HS
#define NBLK  157    // blocks (16 rows each)
#define NTHR  512    // 8 waves: 2 waves/SIMD for latency overlap
#define ROWS  16     // nodes per block (MFMA M-tile)
#define MPAD  (NBLK * ROWS)   // 2512 padded rows
#define KPAD  2528            // 79*32 (proven adj layout)
#define NCHUNK 79
#define HPAD  36              // fp32 LDS row pad
#define FLAGSTRIDE 16         // uints between flags (64 B)

// Fragment-ordered q slice (ring mode):
//   region r (r=0: h rows 0-15, r=1: h rows 16-31), chunk c (32 nodes),
//   byte addr = r*REGBYTES + c*1024 + lane*16 holds the 16 B MFMA-B fragment
//   for lane `lane` of chunk c. Producer block b (c=b>>1, half=b&1) owns the
//   contiguous 512 B [c*1024+half*512, +512) of each region.
#define REGUS   (NCHUNK * 512)          // region size in ushorts (40448)

// workspace layout (bytes) — identical to prior rounds
#define WS_FLAGS_OFF  0
#define WS_ADJ_OFF    16384
#define WS_ADJ_BYTES  ((size_t)MPAD * KPAD * 2)
#define WS_QT_OFF     (WS_ADJ_OFF + WS_ADJ_BYTES)
#define QT_SLICE      ((size_t)HS * KPAD)
#define WS_NEED_RING  (WS_QT_OFF + (size_t)TT * QT_SLICE * 2)   // ~77.4 MB

typedef __attribute__((ext_vector_type(8))) __bf16 bf16x8;
typedef __attribute__((ext_vector_type(4))) float floatx4;
typedef unsigned short ushort_t;
typedef unsigned long long u64_t;

__device__ __forceinline__ float sigmoid_fast(float v) {
    return 1.0f / (1.0f + __expf(-v));
}
__device__ __forceinline__ float tanh_fast(float v) {
    float e = __expf(2.0f * v);
    return 1.0f - 2.0f / (e + 1.0f);
}
__device__ __forceinline__ ushort_t f2bf(float f) {
    union { float f; unsigned u; } x; x.f = f;
    unsigned r = x.u + 0x7fffu + ((x.u >> 16) & 1u);  // RNE
    return (ushort_t)(r >> 16);
}

// Sentinel: if the cooperative launch is rejected at submit time, out keeps
// 12345.0 -> absmax ~1.23e4 (vs 1.0156 "untouched", 3.9e-3 "correct").
__global__ void sentinel(float* __restrict__ out, int n) {
    int i = blockIdx.x * blockDim.x + threadIdx.x;
    if (i < n) out[i] = 12345.0f;
}

// Per-launch prep (d_ws re-poisoned 0xAA before every timed launch) — R2 form.
__global__ void prep(const float* __restrict__ adj, ushort_t* __restrict__ adj_bf,
                     ushort_t* __restrict__ qT, unsigned* __restrict__ flags) {
    const size_t idx0 = (size_t)blockIdx.x * blockDim.x + threadIdx.x;
    const size_t stride = (size_t)gridDim.x * blockDim.x;
    const size_t total = (size_t)MPAD * KPAD;
    for (size_t idx = idx0; idx < total; idx += stride) {
        int r = (int)(idx / KPAD);
        int k = (int)(idx - (size_t)r * KPAD);
        float v = (r < BSN && k < BSN) ? adj[(size_t)r * BSN + k] : 0.0f;
        adj_bf[idx] = f2bf(v);
    }
    for (size_t idx = idx0; idx < 2 * QT_SLICE; idx += stride) qT[idx] = 0;
    if (idx0 < NBLK * FLAGSTRIDE) flags[idx0] = 0;
}

#define QLOAD(p) __hip_atomic_load((p), __ATOMIC_RELAXED, __HIP_MEMORY_SCOPE_AGENT)

// P2, fragment layout on BOTH operands: chunk c's A-fragment (adj, LDS) and
// B-fragments (q, LLC) for this lane live at base + c*512 ushorts. Every
// LDS/global access is a 64-lane x 16 B sequential burst — conflict-free.
template<int NC>
__device__ __forceinline__ void p2_frag(const ushort_t* __restrict__ afrag,
                                        const ushort_t* __restrict__ q0,
                                        const ushort_t* __restrict__ q1,
                                        const int cbeg,
                                        floatx4& acc0, floatx4& acc1) {
    bf16x8 b0[NC], b1[NC];
#pragma unroll
    for (int i = 0; i < NC; i++) {
        b0[i] = *(const bf16x8*)(q0 + (size_t)(cbeg + i) * 512);
        b1[i] = *(const bf16x8*)(q1 + (size_t)(cbeg + i) * 512);
    }
#pragma unroll
    for (int i = 0; i < NC; i++) {
        bf16x8 av = *(const bf16x8*)(afrag + (size_t)(cbeg + i) * 512);
        acc0 = __builtin_amdgcn_mfma_f32_16x16x32_bf16(av, b0[i], acc0, 0, 0, 0);
        acc1 = __builtin_amdgcn_mfma_f32_16x16x32_bf16(av, b1[i], acc1, 0, 0, 0);
    }
}

// Persistent cooperative kernel, 512 threads (8 waves), block b owns nodes
// [16b,16b+16).
// R6 = R5 protocol (flags, drain, per-wave poll, dedicated publish wave0,
// part[] ping-pong) with:
//   * adj staged into LDS in MFMA-A-FRAGMENT order -> P2 LDS reads are
//     sequential 1 KB bursts, bank-conflict-free (was ~556 conflict-cyc/step)
//   * W_q in pinned VGPRs (P1b loses its 8 LDS reads on the serial path)
//   * out flush moved to wave0's idle slot (removes the 1/16-step barrier
//     and takes the flush off P2-carrying wave7)
//   * parity-path placeholder-store bug removed
template<bool RING>
__global__ void __launch_bounds__(NTHR, 2) rgcn_main(
    const float* __restrict__ x,      // [BSN][TT][DIN]
    const float* __restrict__ W_ih,   // [DIN][G4]
    const float* __restrict__ W_hh,   // [HS][G4]
    const float* __restrict__ bias,   // [G4]
    const float* __restrict__ W_q,    // [HS][HS]
    const float* __restrict__ b_q,    // [HS]
    const float* __restrict__ W_d,    // [HS]
    const float* __restrict__ b_d,    // [1]
    const ushort_t* __restrict__ adj_bf, // [MPAD][KPAD] bf16
    ushort_t* __restrict__ qT,        // ring: [TT] fragment slices; parity: [2][HS][KPAD]
    unsigned* __restrict__ flags,     // [NBLK] generation flags, FLAGSTRIDE apart
    float* __restrict__ out)          // [BSN][TT]
{
    const int tid  = threadIdx.x;
    const int blk  = blockIdx.x;
    const int base = blk * ROWS;
    const int wv   = tid >> 6;        // wave 0..7
    const int lane = tid & 63;

    __shared__ __align__(16) ushort_t adj_lds[NCHUNK * 512];  // 79 KB, fragment order
    __shared__ __align__(16) float x_lds[ROWS][DIN];
    __shared__ __align__(16) float h_lds[ROWS][HPAD];
    __shared__ __align__(16) float c_lds[ROWS][HPAD];         // parity path only
    __shared__ __align__(16) float q_lds[ROWS][HPAD];
    __shared__ __align__(16) float out_lds[ROWS][16];         // 16-step out buffer
    __shared__ float gates_lds[ROWS][G4];
    __shared__ float part[2][7][2][16][16];   // ping-pong, waves 1-7, 28 KB

    // ---- per-thread weights, pinned (opaque defs, no remat) ----
    const int u2 = tid & 63;
    float wih0[DIN], wih1[DIN], whh0[HS], whh1[HS];
#pragma unroll
    for (int k = 0; k < DIN; k++) {
        wih0[k] = W_ih[k*G4 + u2]; wih1[k] = W_ih[k*G4 + u2 + 64];
        asm volatile("" : "+v"(wih0[k]), "+v"(wih1[k]));
    }
#pragma unroll
    for (int k = 0; k < HS; k++) {
        whh0[k] = W_hh[k*G4 + u2]; whh1[k] = W_hh[k*G4 + u2 + 64];
        asm volatile("" : "+v"(whh0[k]), "+v"(whh1[k]));
    }
    const float bu0 = bias[u2], bu1 = bias[u2 + 64];

    // P1b/P3 mapping: thread = (node nq = tid>>5, hidden hq = tid&31) — wave-local
    const int hq = tid & 31;
    const int nq = tid >> 5;
    const float bqv = b_q[hq];
    const float wdv = W_d[hq];
    const float bdv = b_d[0];
    float c_reg = 0.0f;               // cell state in a register (ring path)

    // W_q column for this thread's hq, pinned in VGPRs (P1b register FMAs)
    float wqr[HS];
#pragma unroll
    for (int k = 0; k < HS; k++) {
        wqr[k] = W_q[k*HS + hq];
        asm volatile("" : "+v"(wqr[k]));
    }

    // chunk split for waves 1-7: 12,12,12,11,11,11,10 (sum 79)
    int cbeg = 0, nch = 0;
    if (wv >= 1 && wv <= 3)      { cbeg = (wv - 1) * 12;      nch = 12; }
    else if (wv >= 4 && wv <= 6) { cbeg = 36 + (wv - 4) * 11; nch = 11; }
    else if (wv == 7)            { cbeg = 69;                 nch = 10; }
    // producers for this wave's chunks: [2*cbeg, 2*(cbeg+nch)) capped at NBLK
    const int pollbase = 2 * cbeg;
    const int pollcnt  = (wv == 0) ? 0
                       : ((2 * (cbeg + nch) < NBLK ? 2 * (cbeg + nch) : NBLK) - pollbase);
    const unsigned* pollf = flags + (size_t)(pollbase + lane) * FLAGSTRIDE;
    const bool dopoll = (wv >= 1) && (lane < pollcnt);

    // x ownership (ring): wave w>=1 stages nodes 2w,2w+1; waves 1,2 also 0,1
    int xnode = -1, xk = lane & 15;
    if (wv >= 1 && lane < 32)                   xnode = 2*wv + (lane >> 4);
    else if ((wv == 1 || wv == 2) && lane < 48) xnode = wv - 1;
    const int xgn = base + xnode;
    const bool xok = (xnode >= 0) && (xgn < BSN);

    // ---- stage adj to LDS once, in MFMA-A-fragment order ----
    // uint4 o of row r holds cols [o*8, o*8+8) -> chunk c=o>>2, k-group kb=o&3;
    // fragment position: lane l = kb*16 + r, ushort offset c*512 + l*8.
    {
        const int n16_per_row = KPAD / 8;           // 316 uint4 per row
        for (int i = tid; i < ROWS * n16_per_row; i += NTHR) {
            int r = i / n16_per_row, o = i - r * n16_per_row;
            int c = o >> 2, kb = o & 3;
            *(uint4*)(adj_lds + (size_t)c * 512 + (size_t)(kb * 16 + r) * 8) =
                ((const uint4*)(adj_bf + (size_t)(base + r) * KPAD))[o];
        }
    }
    for (int i = tid; i < ROWS * HPAD; i += NTHR) {
        (&h_lds[0][0])[i] = 0.0f;
        (&c_lds[0][0])[i] = 0.0f;
    }
    __syncthreads();

    // gates helper: computes both gate halves for node nn (reads x_lds/h_lds)
    auto do_gates = [&](int nn) {
        float a0 = bu0, a1 = bu1;
#pragma unroll
        for (int k4 = 0; k4 < DIN/4; k4++) {
            float4 xv = *(const float4*)&x_lds[nn][k4*4];
            a0 = fmaf(xv.x, wih0[k4*4+0], a0); a1 = fmaf(xv.x, wih1[k4*4+0], a1);
            a0 = fmaf(xv.y, wih0[k4*4+1], a0); a1 = fmaf(xv.y, wih1[k4*4+1], a1);
            a0 = fmaf(xv.z, wih0[k4*4+2], a0); a1 = fmaf(xv.z, wih1[k4*4+2], a1);
            a0 = fmaf(xv.w, wih0[k4*4+3], a0); a1 = fmaf(xv.w, wih1[k4*4+3], a1);
        }
#pragma unroll
        for (int k4 = 0; k4 < HS/4; k4++) {
            float4 hv = *(const float4*)&h_lds[nn][k4*4];
            a0 = fmaf(hv.x, whh0[k4*4+0], a0); a1 = fmaf(hv.x, whh1[k4*4+0], a1);
            a0 = fmaf(hv.y, whh0[k4*4+1], a0); a1 = fmaf(hv.y, whh1[k4*4+1], a1);
            a0 = fmaf(hv.z, whh0[k4*4+2], a0); a1 = fmaf(hv.z, whh1[k4*4+2], a1);
            a0 = fmaf(hv.w, whh0[k4*4+3], a0); a1 = fmaf(hv.w, whh1[k4*4+3], a1);
        }
        gates_lds[nn][u2]      = sigmoid_fast(a0);
        gates_lds[nn][u2 + 64] = (u2 < HS) ? tanh_fast(a1) : sigmoid_fast(a1);
    };

    // P1b helper: q = tanh(h @ W_q + b_q), register weights
    auto do_p1b = [&]() {
        float a = bqv;
#pragma unroll
        for (int k4 = 0; k4 < HS/4; k4++) {
            float4 hv = *(const float4*)&h_lds[nq][k4*4];
            a = fmaf(hv.x, wqr[k4*4+0], a);
            a = fmaf(hv.y, wqr[k4*4+1], a);
            a = fmaf(hv.z, wqr[k4*4+2], a);
            a = fmaf(hv.w, wqr[k4*4+3], a);
        }
        q_lds[nq][hq] = tanh_fast(a);
    };

    if constexpr (RING) {
        // x prefetch for t = 0
        float xreg = xok ? x[(size_t)xgn * (TT*DIN) + xk] : 0.0f;

        // publish constants (wave0): block b -> chunk c=b>>1, half=b&1
        const int pc    = blk >> 1;
        const int phalf = blk & 1;
        const int preg  = lane >> 5;       // region 0/1
        const int pidx  = lane & 31;
        const int ph    = (pidx & 15) + 16 * preg;   // q_lds h col
        const int pln0  = (pidx >> 4) * 8;           // first of 8 nodes

        for (int t = 0; t < TT; t++) {
            const unsigned phase = (unsigned)(t + 1);
            const ushort_t* qslice = qT + (size_t)t * QT_SLICE;

            do_p1b();
            __syncthreads();   // barrier A: q_lds complete; orders prior P3 writes too

            if (wv == 0) {
                // ---- dedicated publish wave: 2x 8B atomic stores into this
                //      block's contiguous 512 B strip of each region ----
                unsigned d[4];
#pragma unroll
                for (int j = 0; j < 4; j++) {
                    const int n0 = pln0 + 2*j;
                    d[j] = (unsigned)f2bf(q_lds[n0][ph])
                         | ((unsigned)f2bf(q_lds[n0 + 1][ph]) << 16);
                }
                u64_t v0 = (u64_t)d[0] | ((u64_t)d[1] << 32);
                u64_t v1 = (u64_t)d[2] | ((u64_t)d[3] << 32);
                u64_t* dst = (u64_t*)((ushort_t*)qslice + (size_t)preg * REGUS
                                      + (size_t)pc * 512 + phalf * 256 + pidx * 8);
                __hip_atomic_store(dst,     v0, __ATOMIC_RELAXED, __HIP_MEMORY_SCOPE_AGENT);
                __hip_atomic_store(dst + 1, v1, __ATOMIC_RELAXED, __HIP_MEMORY_SCOPE_AGENT);
                asm volatile("s_waitcnt vmcnt(0)" ::: "memory");
                if (lane == 0) {
                    __hip_atomic_store(flags + blk * FLAGSTRIDE, phase,
                                       __ATOMIC_RELAXED, __HIP_MEMORY_SCOPE_AGENT);
                }
                // ---- idle slot: flush previous 16-step out window ----
                if (t >= 16 && (t & 15) == 0) {
                    const int node = lane >> 2, qtr = lane & 3;
                    const int gn = base + node;
                    if (gn < BSN) {
                        *(float4*)(out + (size_t)gn * TT + (t - 16) + qtr * 4) =
                            *(const float4*)&out_lds[node][qtr * 4];
                    }
                }
            } else {
                // ---- shadow: x_lds write (prefetched) + next prefetch + gates ----
                if (xnode >= 0) {
                    x_lds[xnode][xk] = xok ? xreg : 0.0f;
                    const int tn = (t + 1 < TT) ? (t + 1) : (TT - 1);
                    if (xok) xreg = x[(size_t)xgn * (TT*DIN) + (size_t)tn * DIN + xk];
                }
                do_gates(2*wv);
                do_gates(2*wv + 1);
                if (wv <= 2) do_gates(wv - 1);   // cover wave 0's nodes
            }

            // ---- per-wave poll of this wave's producers ----
            if (dopoll) {
                while (QLOAD(pollf) < phase) {}
            }

            // ---- P2 (waves 1-7): agg = adj(LDS frag) @ q(LLC frag) ----
            if (wv >= 1) {
                floatx4 acc0 = {0.f,0.f,0.f,0.f}, acc1 = {0.f,0.f,0.f,0.f};
                const int mcol = lane & 15;
                const int kb   = lane >> 4;
                const ushort_t* afrag = adj_lds + (size_t)lane * 8;
                const ushort_t* q0 = qslice + (size_t)lane * 8;
                const ushort_t* q1 = qslice + (size_t)REGUS + (size_t)lane * 8;
                if (wv <= 3)      p2_frag<12>(afrag, q0, q1, cbeg, acc0, acc1);
                else if (wv <= 6) p2_frag<11>(afrag, q0, q1, cbeg, acc0, acc1);
                else              p2_frag<10>(afrag, q0, q1, cbeg, acc0, acc1);
#pragma unroll
                for (int r = 0; r < 4; r++) {
                    part[t & 1][wv - 1][0][kb*4 + r][mcol] = acc0[r];
                    part[t & 1][wv - 1][1][kb*4 + r][mcol] = acc1[r];
                }
            }
            __syncthreads();   // RAW: part[] (P2 -> P3)

            // ---- P3: cell/hidden update + buffered out head ----
            {
                const int ntile = hq >> 4, col = hq & 15;
                float agg = 0.0f;
#pragma unroll
                for (int j = 0; j < 7; j++) agg += part[t & 1][j][ntile][nq][col];
                float iv = gates_lds[nq][hq];
                float fv = gates_lds[nq][HS + hq];
                float gv = gates_lds[nq][2*HS + hq];
                float ov = gates_lds[nq][3*HS + hq];
                float cv = fv * (c_reg + agg) + iv * gv;
                float hvv = ov * tanh_fast(cv);
                c_reg = cv;
                h_lds[nq][hq] = hvv;
                float p = hvv * wdv;
                p += __shfl_xor(p, 16);
                p += __shfl_xor(p, 8);
                p += __shfl_xor(p, 4);
                p += __shfl_xor(p, 2);
                p += __shfl_xor(p, 1);
                if (hq == 0) out_lds[nq][t & 15] = p + bdv;
            }
        }
        // ---- final out window [TT-16, TT) ----
        __syncthreads();
        if (wv == 0) {
            const int node = lane >> 2, qtr = lane & 3;
            const int gn = base + node;
            if (gn < BSN) {
                *(float4*)(out + (size_t)gn * TT + (TT - 16) + qtr * 4) =
                    *(const float4*)&out_lds[node][qtr * 4];
            }
        }
    } else {
        // ================= parity fallback: R2-proven flag structure =================
        for (int t = 0; t < TT; t++) {
            const unsigned phase = (unsigned)(t + 1);
            ushort_t* qbuf = qT + (size_t)(t & 1) * QT_SLICE;

            do_p1b();
            __syncthreads();

            if (tid < 256) {
                const int h0 = tid >> 3;
                const int pr = tid & 7;
                unsigned val = (unsigned)f2bf(q_lds[2*pr][h0])
                             | ((unsigned)f2bf(q_lds[2*pr + 1][h0]) << 16);
                unsigned* p = (unsigned*)(qbuf + (size_t)h0 * KPAD + base) + pr;
                __hip_atomic_store(p, val, __ATOMIC_RELAXED, __HIP_MEMORY_SCOPE_AGENT);
            }
            if (lane < 32) {
                const int node = 2*wv + (lane >> 4), k = lane & 15;
                const int gn = base + node;
                x_lds[node][k] = (gn < BSN) ? x[(size_t)gn * (TT*DIN) + (size_t)t*DIN + k] : 0.0f;
            }
            do_gates(2*wv);
            do_gates(2*wv + 1);
            asm volatile("s_waitcnt vmcnt(0)" ::: "memory");
            __syncthreads();
            if (tid == 0) {
                __hip_atomic_store(flags + blk * FLAGSTRIDE, phase,
                                   __ATOMIC_RELAXED, __HIP_MEMORY_SCOPE_AGENT);
            }
            if (tid < NBLK) {
                const unsigned* f = flags + tid * FLAGSTRIDE;
                while (QLOAD(f) < phase) {}
            }
            __syncthreads();

            {
                floatx4 acc0 = {0.f,0.f,0.f,0.f}, acc1 = {0.f,0.f,0.f,0.f};
                const int mcol = lane & 15;
                const int kb   = lane >> 4;
                const ushort_t* afrag = adj_lds + (size_t)lane * 8;   // fragment order
                const u64_t* q0 = (const u64_t*)(qbuf + (size_t)mcol        * KPAD) + kb*2;
                const u64_t* q1 = (const u64_t*)(qbuf + (size_t)(mcol + 16) * KPAD) + kb*2;
                const int cb2 = wv * 10;
                const int ce2 = (cb2 + 10 < NCHUNK) ? cb2 + 10 : NCHUNK;
                for (int c = cb2; c < ce2; c++) {
                    bf16x8 av = *(const bf16x8*)(afrag + (size_t)c * 512);
                    union { u64_t u[2]; bf16x8 v; } b0, b1;
                    b0.u[0] = QLOAD(q0 + c*8);
                    b0.u[1] = QLOAD(q0 + c*8 + 1);
                    b1.u[0] = QLOAD(q1 + c*8);
                    b1.u[1] = QLOAD(q1 + c*8 + 1);
                    acc0 = __builtin_amdgcn_mfma_f32_16x16x32_bf16(av, b0.v, acc0, 0, 0, 0);
                    acc1 = __builtin_amdgcn_mfma_f32_16x16x32_bf16(av, b1.v, acc1, 0, 0, 0);
                }
                // flat per-wave slots in part[] (8 waves x 512 floats)
                float* pw = &part[0][0][0][0][0] + (size_t)wv * 2 * 16 * 16;
#pragma unroll
                for (int r = 0; r < 4; r++) {
                    pw[(0*16 + kb*4 + r) * 16 + mcol] = acc0[r];
                    pw[(1*16 + kb*4 + r) * 16 + mcol] = acc1[r];
                }
            }
            __syncthreads();

            {
                const int ntile = hq >> 4, col = hq & 15;
                float agg = 0.0f;
                const float* pbase = &part[0][0][0][0][0];
#pragma unroll
                for (int w = 0; w < 8; w++) {
                    agg += pbase[(size_t)w * 2 * 16 * 16 + (ntile*16 + nq) * 16 + col];
                }
                float iv = gates_lds[nq][hq];
                float fv = gates_lds[nq][HS + hq];
                float gv = gates_lds[nq][2*HS + hq];
                float ov = gates_lds[nq][3*HS + hq];
                float cv = fv * (c_lds[nq][hq] + agg) + iv * gv;
                float hv = ov * tanh_fast(cv);
                c_lds[nq][hq] = cv;
                h_lds[nq][hq] = hv;
                float p = hv * wdv;
                p += __shfl_xor(p, 16);
                p += __shfl_xor(p, 8);
                p += __shfl_xor(p, 4);
                p += __shfl_xor(p, 2);
                p += __shfl_xor(p, 1);
                if (hq == 0) {
                    int gn = base + nq;
                    if (gn < BSN) out[(size_t)gn * TT + t] = p + bdv;
                }
            }
            __syncthreads();
        }
    }
}

extern "C" void kernel_launch(void* const* d_in, const int* in_sizes, int n_in,
                              void* d_out, int out_size, void* d_ws, size_t ws_size,
                              hipStream_t stream) {
    const float* x    = (const float*)d_in[0];
    const float* adj  = (const float*)d_in[1];
    const float* W_ih = (const float*)d_in[2];
    const float* W_hh = (const float*)d_in[3];
    const float* bias = (const float*)d_in[4];
    const float* W_q  = (const float*)d_in[5];
    const float* b_q  = (const float*)d_in[6];
    const float* W_d  = (const float*)d_in[7];
    const float* b_d  = (const float*)d_in[8];
    float* out = (float*)d_out;

    unsigned* flags = (unsigned*)((char*)d_ws + WS_FLAGS_OFF);
    ushort_t* adj_bf = (ushort_t*)((char*)d_ws + WS_ADJ_OFF);
    ushort_t* qT = (ushort_t*)((char*)d_ws + WS_QT_OFF);

    const bool ring = (ws_size >= WS_NEED_RING);   // constant across calls -> graph-safe

    // sentinel first: if the cooperative launch below is rejected, out keeps 12345.0
    hipLaunchKernelGGL(sentinel, dim3((out_size + 255) / 256), dim3(256), 0, stream,
                       out, out_size);
    hipLaunchKernelGGL(prep, dim3(2048), dim3(256), 0, stream, adj, adj_bf, qT, flags);

    const ushort_t* adj_bf_c = adj_bf;
    void* args[] = {
        (void*)&x, (void*)&W_ih, (void*)&W_hh, (void*)&bias, (void*)&W_q,
        (void*)&b_q, (void*)&W_d, (void*)&b_d, (void*)&adj_bf_c, (void*)&qT,
        (void*)&flags, (void*)&out
    };
    if (ring) {
        hipLaunchCooperativeKernel((void*)&rgcn_main<true>, dim3(NBLK), dim3(NTHR),
                                   args, 0, stream);
    } else {
        hipLaunchCooperativeKernel((void*)&rgcn_main<false>, dim3(NBLK), dim3(NTHR),
                                   args, 0, stream);
    }
}